// Round 7
// baseline (132.541 us; speedup 1.0000x reference)
//
#include <hip/hip_runtime.h>

#define DEV static __device__ __forceinline__

// Skewed LDS addressing: physical = j + j/32. Breaks the 12/24-float lane
// strides into ~2-way conflicts. Max phys for T=4096: 4095 + 127 = 4222 < 4224.
#define SKEW(j) ((j) + ((j) >> 5))

// ---------------------------------------------------------------------------
// 4-wave-per-series kernel (P == 12, T % 4 == 0, 12 <= T <= 4096).
//
// One block (256 threads = 4 waves) owns one series; only err is staged to
// LDS (16.9 KB + 384 B totals -> LDS permits 8 blocks/CU; VGPRs cap ~6
// waves/SIMD). The 341 periods are split over 256 lanes (m in {base,base+1}).
//
// The ETS state x = (level, trend, s[0..11]) evolves affinely; over whole
// periods the homogeneous map lives in the closed 15-param family
//   l -> l + L*tr + sum_j c_j s_j ; tr -> tr + f*sum_j s_j ; s_j -> d*s_j.
// Per-lane map: analytic geometric sums of d = 1-gamma; particular part:
// pass1 recurrence from zero state. Internal per-wave 6-round Kogge-Stone
// scan composes 64 lane maps; wave totals are exchanged via LDS and applied
// to x0 as STATES (cheap); pass2 writes `cur` into the consumed err slots;
// store-out fuses y = cur + 0.1*obs with a coalesced obs read.
// ---------------------------------------------------------------------------
__global__ __launch_bounds__(256, 6) void ets_wave4(
    const float* __restrict__ alpha_, const float* __restrict__ beta_,
    const float* __restrict__ gamma_, const float* __restrict__ lvl0,
    const float* __restrict__ tr0, const float* __restrict__ seas0,
    const float* __restrict__ obs, const float* __restrict__ err,
    float* __restrict__ out, int T)
{
  __shared__ float er_s[4224];     // err, recycled for `cur` in pass2
  __shared__ float totals[3][32];  // wave 0..2 inclusive maps (29 floats)

  const int n = blockIdx.x;
  const int tid = threadIdx.x;
  const int lane = tid & 63;
  const int wv = tid >> 6;

  const float4* ER4 = reinterpret_cast<const float4*>(err + (size_t)n * T);
  const float4* OB4 = reinterpret_cast<const float4*>(obs + (size_t)n * T);
  const int nf4 = T >> 2;

  // Coalesced stage-in.
  for (int i = tid; i < nf4; i += 256) {
    float4 e = ER4[i];
    int j = i << 2;
    er_s[SKEW(j + 0)] = e.x; er_s[SKEW(j + 1)] = e.y;
    er_s[SKEW(j + 2)] = e.z; er_s[SKEW(j + 3)] = e.w;
  }

  const float a = alpha_[n], b = beta_[n], g = gamma_[n];
  const float ab = a * b, ig = 1.0f - g;

  const int nper = T / 12;
  const int base = nper >> 8, rem = nper & 255;
  const int m  = base + (tid < rem ? 1 : 0);     // periods this lane owns
  const int p0 = tid * base + min(tid, rem);     // first period
  const int t0 = p0 * 12;

  __syncthreads();

  // ---- pass1: particular solution from zero state -------------------------
  float l = 0.f, tr = 0.f, s[12];
#pragma unroll
  for (int j = 0; j < 12; ++j) s[j] = 0.f;
  {
    int t = t0;
    for (int u = 0; u < m; ++u, t += 12) {
#pragma unroll
      for (int j = 0; j < 12; ++j) {
        float e = er_s[SKEW(t + j)];
        float se = s[j] + e;
        float lt = l + tr;
        l  = fmaf(a, se, lt);
        tr = fmaf(ab, se, tr);
        s[j] = fmaf(g, e, ig * s[j]);
      }
    }
  }

  // ---- analytic homogeneous map for this lane's m periods -----------------
  float S0 = 0.f, S1 = 0.f, dk = 1.f;
  for (int k = 0; k < m; ++k) { S0 += dk; S1 += (float)k * dk; dk *= ig; }
  float GL = 12.0f * (float)m;    // l += GL * tr coefficient
  float Gd = dk;                  // seasonal decay d^m  (m==0 -> identity)
  float Gf = ab * S0;             // tr += Gf * sum(s)
  float Gc[12];
#pragma unroll
  for (int j = 0; j < 12; ++j)
    Gc[j] = fmaf(a, S0, ab * ((GL - 1.0f - (float)j) * S0 - 12.0f * S1));
  float Pl = l, Pt = tr, Ps[12];
#pragma unroll
  for (int j = 0; j < 12; ++j) Ps[j] = s[j];

  // ---- per-wave Kogge-Stone inclusive scan of affine maps -----------------
  // compose(first = earlier lanes, second = current):
  //   L' = oL + L;  d' = od*d;  f' = of + f*od;  c'_j = oc_j + L*of + c_j*od
  //   ps'_j = d*ops_j + ps_j;  pt' = opt + f*sum(ops) + pt;
  //   pl' = opl + L*opt + dot(c, ops) + pl
#pragma unroll
  for (int dlt = 1; dlt < 64; dlt <<= 1) {
    float oL  = __shfl_up(GL, dlt, 64);
    float od  = __shfl_up(Gd, dlt, 64);
    float of  = __shfl_up(Gf, dlt, 64);
    float oPl = __shfl_up(Pl, dlt, 64);
    float oPt = __shfl_up(Pt, dlt, 64);
    float oc[12], oPs[12];
#pragma unroll
    for (int j = 0; j < 12; ++j) {
      oc[j]  = __shfl_up(Gc[j], dlt, 64);
      oPs[j] = __shfl_up(Ps[j], dlt, 64);
    }
    if (lane >= dlt) {
      float sum_oPs = 0.f, dot = 0.f;
#pragma unroll
      for (int j = 0; j < 12; ++j) {
        sum_oPs += oPs[j];
        dot = fmaf(Gc[j], oPs[j], dot);
      }
      float nPl = oPl + GL * oPt + dot + Pl;
      float nPt = oPt + Gf * sum_oPs + Pt;
#pragma unroll
      for (int j = 0; j < 12; ++j) {
        Ps[j] = fmaf(Gd, oPs[j], Ps[j]);
        Gc[j] = oc[j] + GL * of + Gc[j] * od;
      }
      Pl = nPl; Pt = nPt;
      Gf = of + Gf * od;
      Gd = od * Gd;
      GL = oL + GL;
    }
  }

  // ---- exchange wave totals (inclusive map of each wave's last lane) ------
  if (lane == 63 && wv < 3) {
    float* tw = totals[wv];
    tw[0] = GL; tw[1] = Gd; tw[2] = Gf; tw[3] = Pl; tw[4] = Pt;
#pragma unroll
    for (int j = 0; j < 12; ++j) { tw[5 + j] = Gc[j]; tw[17 + j] = Ps[j]; }
  }
  __syncthreads();

  // ---- wave-start state X_w = totals[wv-1] o ... o totals[0] (x0) ---------
  float xl = lvl0[n], xt = tr0[n], xs[12];
#pragma unroll
  for (int j = 0; j < 12; ++j) xs[j] = seas0[(size_t)n * 12 + j];
  for (int v = 0; v < wv; ++v) {          // wave-uniform trip count (0..3)
    const float* tw = totals[v];
    float ss = 0.f, cdot = 0.f;
#pragma unroll
    for (int j = 0; j < 12; ++j) {
      ss += xs[j];
      cdot = fmaf(tw[5 + j], xs[j], cdot);
    }
    float nxl = xl + tw[0] * xt + cdot + tw[3];
    float nxt = fmaf(tw[2], ss, xt) + tw[4];
#pragma unroll
    for (int j = 0; j < 12; ++j) xs[j] = fmaf(tw[1], xs[j], tw[17 + j]);
    xl = nxl; xt = nxt;
  }

  // ---- apply inclusive map to X_w -> state AFTER this lane's chunk --------
  float ss = 0.f, cdot = 0.f;
#pragma unroll
  for (int j = 0; j < 12; ++j) { ss += xs[j]; cdot = fmaf(Gc[j], xs[j], cdot); }
  float yl = xl + GL * xt + cdot + Pl;
  float yt = xt + Gf * ss + Pt;
  float ys[12];
#pragma unroll
  for (int j = 0; j < 12; ++j) ys[j] = fmaf(Gd, xs[j], Ps[j]);

  // exclusive shift: lane's true initial state = previous lane's inclusive;
  // lane 0 of each wave takes the wave-start state X_w.
  l  = __shfl_up(yl, 1, 64);
  tr = __shfl_up(yt, 1, 64);
#pragma unroll
  for (int j = 0; j < 12; ++j) s[j] = __shfl_up(ys[j], 1, 64);
  if (lane == 0) {
    l = xl; tr = xt;
#pragma unroll
    for (int j = 0; j < 12; ++j) s[j] = xs[j];
  }

  // ---- pass2: write `cur` into the consumed err slots ---------------------
  {
    int t = t0;
    for (int u = 0; u < m; ++u, t += 12) {
#pragma unroll
      for (int j = 0; j < 12; ++j) {
        int ad = SKEW(t + j);
        float e = er_s[ad];
        float lt = l + tr;
        float cur = lt + s[j];
        er_s[ad] = cur;                 // y minus the 0.1*obs term
        float se = s[j] + e;
        l  = fmaf(a, se, lt);
        tr = fmaf(ab, se, tr);
        s[j] = fmaf(g, e, ig * s[j]);
      }
    }
  }
  // tail (< 12 steps, slot phase 0) continues from the last lane's state
  if (tid == 255) {
    int tt = nper * 12;
    int tail = T - tt;
#pragma unroll
    for (int j = 0; j < 11; ++j) {
      if (j < tail) {
        int ad = SKEW(tt + j);
        float e = er_s[ad];
        float lt = l + tr;
        float cur = lt + s[j];
        er_s[ad] = cur;
        float se = s[j] + e;
        l  = fmaf(a, se, lt);
        tr = fmaf(ab, se, tr);
        s[j] = fmaf(g, e, ig * s[j]);
      }
    }
  }

  __syncthreads();

  // Coalesced store-out, fusing y = cur + 0.1*obs with a coalesced obs read.
  float4* Y4 = reinterpret_cast<float4*>(out + (size_t)n * T);
  for (int i = tid; i < nf4; i += 256) {
    float4 o = OB4[i];
    int j = i << 2;
    float4 v = make_float4(fmaf(o.x, 0.1f, er_s[SKEW(j + 0)]),
                           fmaf(o.y, 0.1f, er_s[SKEW(j + 1)]),
                           fmaf(o.z, 0.1f, er_s[SKEW(j + 2)]),
                           fmaf(o.w, 0.1f, er_s[SKEW(j + 3)]));
    Y4[i] = v;
  }
}

// ---------------------------------------------------------------------------
// Generic fallback (any P/T): one thread per series, seasonal state in LDS.
// ---------------------------------------------------------------------------
__global__ void ets_gen(
    const float* __restrict__ alpha_, const float* __restrict__ beta_,
    const float* __restrict__ gamma_, const float* __restrict__ lvl0,
    const float* __restrict__ tr0, const float* __restrict__ seas0,
    const float* __restrict__ obs, const float* __restrict__ err,
    float* __restrict__ out, int N, int T, int P)
{
  extern __shared__ float smem[];
  int n = blockIdx.x * blockDim.x + threadIdx.x;
  if (n >= N) return;
  float* s = smem + (size_t)threadIdx.x * P;
  for (int j = 0; j < P; ++j) s[j] = seas0[(size_t)n * P + j];

  float a = alpha_[n], b = beta_[n], g = gamma_[n];
  float ia = 1.0f - a, ib = 1.0f - b, ig = 1.0f - g;
  float level = lvl0[n], trend = tr0[n];

  const float* on = obs + (size_t)n * T;
  const float* er = err + (size_t)n * T;
  float*       yo = out + (size_t)n * T;

  int idx = 0;
  for (int t = 0; t < T; ++t) {
    float onj = on[t], ej = er[t];
    float sj  = s[idx];
    float cur = level + trend + sj;
    yo[t] = fmaf(onj, 0.1f, cur);
    float lt  = level + trend;
    float nl  = fmaf(a, cur + ej, ia * lt);
    float nt  = fmaf(b, nl - level, ib * trend);
    s[idx]    = fmaf(g, ej, ig * sj);
    level = nl; trend = nt;
    if (++idx == P) idx = 0;
  }
}

extern "C" void kernel_launch(void* const* d_in, const int* in_sizes, int n_in,
                              void* d_out, int out_size, void* d_ws, size_t ws_size,
                              hipStream_t stream) {
  (void)n_in; (void)out_size; (void)d_ws; (void)ws_size;
  const float* alpha = (const float*)d_in[0];
  const float* beta  = (const float*)d_in[1];
  const float* gamma = (const float*)d_in[2];
  const float* lvl0  = (const float*)d_in[3];
  const float* tr0   = (const float*)d_in[4];
  const float* seas0 = (const float*)d_in[5];
  const float* obs   = (const float*)d_in[6];
  const float* err   = (const float*)d_in[7];
  float* y = (float*)d_out;

  int N = in_sizes[0];
  int P = in_sizes[5] / N;
  int T = in_sizes[6] / N;

  if (P == 12 && (T % 4) == 0 && T >= 12 && T <= 4096) {
    ets_wave4<<<dim3(N), dim3(256), 0, stream>>>(
        alpha, beta, gamma, lvl0, tr0, seas0, obs, err, y, T);
  } else {
    int bs = 64;
    size_t sh = (size_t)bs * (size_t)P * sizeof(float);
    ets_gen<<<dim3((N + bs - 1) / bs), dim3(bs), sh, stream>>>(
        alpha, beta, gamma, lvl0, tr0, seas0, obs, err, y, N, T, P);
  }
}

// Round 8
// 57.239 us; speedup vs baseline: 2.3156x; 2.3156x over previous
//
#include <hip/hip_runtime.h>

#define DEV static __device__ __forceinline__

// Skewed LDS addressing: physical = j + j/32. Breaks the 12/24-float lane
// strides into ~2-way conflicts. Max phys for T=4096: 4095 + 127 = 4222 < 4224.
#define SKEW(j) ((j) + ((j) >> 5))

// ---------------------------------------------------------------------------
// 4-wave-per-series kernel (P == 12, T % 4 == 0, 12 <= T <= 4096).
//
// One block (256 threads = 4 waves) owns one series; only err is staged to
// LDS (17.4 KB). The nper periods are split over 256 lanes (m in {base,base+1}).
//
// ROUND-7 FIX: __launch_bounds__(256, 4) (VGPR cap 128), NOT (256, 6): the
// scan's live state needs ~90 VGPRs; cap 85 forced a spill-to-scratch
// catastrophe (WRITE_SIZE 65.5 -> 389 MB, 2.5x slowdown). VGPRs are now the
// occupancy binder at ~4 blocks/CU = 16 waves/CU; LDS would allow 9.
//
// The ETS state x = (level, trend, s[0..11]) evolves affinely; over whole
// periods the homogeneous map lives in the closed 15-param family
//   l -> l + L*tr + sum_j c_j s_j ; tr -> tr + f*sum_j s_j ; s_j -> d*s_j.
// Per-lane map: analytic geometric sums of d = 1-gamma; particular part:
// pass1 recurrence from zero state. Internal per-wave 6-round Kogge-Stone
// scan composes 64 lane maps; wave totals are exchanged via LDS and applied
// to x0 as STATES (cheap); pass2 writes `cur` into the consumed err slots;
// store-out fuses y = cur + 0.1*obs with a coalesced obs read.
// ---------------------------------------------------------------------------
__global__ __launch_bounds__(256, 4) void ets_wave4(
    const float* __restrict__ alpha_, const float* __restrict__ beta_,
    const float* __restrict__ gamma_, const float* __restrict__ lvl0,
    const float* __restrict__ tr0, const float* __restrict__ seas0,
    const float* __restrict__ obs, const float* __restrict__ err,
    float* __restrict__ out, int T)
{
  __shared__ float er_s[4224];     // err, recycled for `cur` in pass2
  __shared__ float totals[3][32];  // wave 0..2 inclusive maps (29 floats)

  const int n = blockIdx.x;
  const int tid = threadIdx.x;
  const int lane = tid & 63;
  const int wv = tid >> 6;

  const float4* ER4 = reinterpret_cast<const float4*>(err + (size_t)n * T);
  const float4* OB4 = reinterpret_cast<const float4*>(obs + (size_t)n * T);
  const int nf4 = T >> 2;

  // Coalesced stage-in.
  for (int i = tid; i < nf4; i += 256) {
    float4 e = ER4[i];
    int j = i << 2;
    er_s[SKEW(j + 0)] = e.x; er_s[SKEW(j + 1)] = e.y;
    er_s[SKEW(j + 2)] = e.z; er_s[SKEW(j + 3)] = e.w;
  }

  const float a = alpha_[n], b = beta_[n], g = gamma_[n];
  const float ab = a * b, ig = 1.0f - g;

  const int nper = T / 12;
  const int base = nper >> 8, rem = nper & 255;
  const int m  = base + (tid < rem ? 1 : 0);     // periods this lane owns
  const int p0 = tid * base + min(tid, rem);     // first period
  const int t0 = p0 * 12;

  __syncthreads();

  // ---- pass1: particular solution from zero state -------------------------
  float l = 0.f, tr = 0.f, s[12];
#pragma unroll
  for (int j = 0; j < 12; ++j) s[j] = 0.f;
  {
    int t = t0;
    for (int u = 0; u < m; ++u, t += 12) {
#pragma unroll
      for (int j = 0; j < 12; ++j) {
        float e = er_s[SKEW(t + j)];
        float se = s[j] + e;
        float lt = l + tr;
        l  = fmaf(a, se, lt);
        tr = fmaf(ab, se, tr);
        s[j] = fmaf(g, e, ig * s[j]);
      }
    }
  }

  // ---- analytic homogeneous map for this lane's m periods -----------------
  float S0 = 0.f, S1 = 0.f, dk = 1.f;
  for (int k = 0; k < m; ++k) { S0 += dk; S1 += (float)k * dk; dk *= ig; }
  float GL = 12.0f * (float)m;    // l += GL * tr coefficient
  float Gd = dk;                  // seasonal decay d^m  (m==0 -> identity)
  float Gf = ab * S0;             // tr += Gf * sum(s)
  float Gc[12];
#pragma unroll
  for (int j = 0; j < 12; ++j)
    Gc[j] = fmaf(a, S0, ab * ((GL - 1.0f - (float)j) * S0 - 12.0f * S1));
  float Pl = l, Pt = tr, Ps[12];
#pragma unroll
  for (int j = 0; j < 12; ++j) Ps[j] = s[j];

  // ---- per-wave Kogge-Stone inclusive scan of affine maps -----------------
  // compose(first = earlier lanes, second = current):
  //   L' = oL + L;  d' = od*d;  f' = of + f*od;  c'_j = oc_j + L*of + c_j*od
  //   ps'_j = d*ops_j + ps_j;  pt' = opt + f*sum(ops) + pt;
  //   pl' = opl + L*opt + dot(c, ops) + pl
#pragma unroll
  for (int dlt = 1; dlt < 64; dlt <<= 1) {
    float oL  = __shfl_up(GL, dlt, 64);
    float od  = __shfl_up(Gd, dlt, 64);
    float of  = __shfl_up(Gf, dlt, 64);
    float oPl = __shfl_up(Pl, dlt, 64);
    float oPt = __shfl_up(Pt, dlt, 64);
    float oc[12], oPs[12];
#pragma unroll
    for (int j = 0; j < 12; ++j) {
      oc[j]  = __shfl_up(Gc[j], dlt, 64);
      oPs[j] = __shfl_up(Ps[j], dlt, 64);
    }
    if (lane >= dlt) {
      float sum_oPs = 0.f, dot = 0.f;
#pragma unroll
      for (int j = 0; j < 12; ++j) {
        sum_oPs += oPs[j];
        dot = fmaf(Gc[j], oPs[j], dot);
      }
      float nPl = oPl + GL * oPt + dot + Pl;
      float nPt = oPt + Gf * sum_oPs + Pt;
#pragma unroll
      for (int j = 0; j < 12; ++j) {
        Ps[j] = fmaf(Gd, oPs[j], Ps[j]);
        Gc[j] = oc[j] + GL * of + Gc[j] * od;
      }
      Pl = nPl; Pt = nPt;
      Gf = of + Gf * od;
      Gd = od * Gd;
      GL = oL + GL;
    }
  }

  // ---- exchange wave totals (inclusive map of each wave's last lane) ------
  if (lane == 63 && wv < 3) {
    float* tw = totals[wv];
    tw[0] = GL; tw[1] = Gd; tw[2] = Gf; tw[3] = Pl; tw[4] = Pt;
#pragma unroll
    for (int j = 0; j < 12; ++j) { tw[5 + j] = Gc[j]; tw[17 + j] = Ps[j]; }
  }
  __syncthreads();

  // ---- wave-start state X_w = totals[wv-1] o ... o totals[0] (x0) ---------
  float xl = lvl0[n], xt = tr0[n], xs[12];
#pragma unroll
  for (int j = 0; j < 12; ++j) xs[j] = seas0[(size_t)n * 12 + j];
  for (int v = 0; v < wv; ++v) {          // wave-uniform trip count (0..3)
    const float* tw = totals[v];
    float ss = 0.f, cdot = 0.f;
#pragma unroll
    for (int j = 0; j < 12; ++j) {
      ss += xs[j];
      cdot = fmaf(tw[5 + j], xs[j], cdot);
    }
    float nxl = xl + tw[0] * xt + cdot + tw[3];
    float nxt = fmaf(tw[2], ss, xt) + tw[4];
#pragma unroll
    for (int j = 0; j < 12; ++j) xs[j] = fmaf(tw[1], xs[j], tw[17 + j]);
    xl = nxl; xt = nxt;
  }

  // ---- apply inclusive map to X_w -> state AFTER this lane's chunk --------
  float ss = 0.f, cdot = 0.f;
#pragma unroll
  for (int j = 0; j < 12; ++j) { ss += xs[j]; cdot = fmaf(Gc[j], xs[j], cdot); }
  float yl = xl + GL * xt + cdot + Pl;
  float yt = xt + Gf * ss + Pt;
  float ys[12];
#pragma unroll
  for (int j = 0; j < 12; ++j) ys[j] = fmaf(Gd, xs[j], Ps[j]);

  // exclusive shift: lane's true initial state = previous lane's inclusive;
  // lane 0 of each wave takes the wave-start state X_w.
  l  = __shfl_up(yl, 1, 64);
  tr = __shfl_up(yt, 1, 64);
#pragma unroll
  for (int j = 0; j < 12; ++j) s[j] = __shfl_up(ys[j], 1, 64);
  if (lane == 0) {
    l = xl; tr = xt;
#pragma unroll
    for (int j = 0; j < 12; ++j) s[j] = xs[j];
  }

  // ---- pass2: write `cur` into the consumed err slots ---------------------
  {
    int t = t0;
    for (int u = 0; u < m; ++u, t += 12) {
#pragma unroll
      for (int j = 0; j < 12; ++j) {
        int ad = SKEW(t + j);
        float e = er_s[ad];
        float lt = l + tr;
        float cur = lt + s[j];
        er_s[ad] = cur;                 // y minus the 0.1*obs term
        float se = s[j] + e;
        l  = fmaf(a, se, lt);
        tr = fmaf(ab, se, tr);
        s[j] = fmaf(g, e, ig * s[j]);
      }
    }
  }
  // tail (< 12 steps, slot phase 0) continues from the last lane's state
  if (tid == 255) {
    int tt = nper * 12;
    int tail = T - tt;
#pragma unroll
    for (int j = 0; j < 11; ++j) {
      if (j < tail) {
        int ad = SKEW(tt + j);
        float e = er_s[ad];
        float lt = l + tr;
        float cur = lt + s[j];
        er_s[ad] = cur;
        float se = s[j] + e;
        l  = fmaf(a, se, lt);
        tr = fmaf(ab, se, tr);
        s[j] = fmaf(g, e, ig * s[j]);
      }
    }
  }

  __syncthreads();

  // Coalesced store-out, fusing y = cur + 0.1*obs with a coalesced obs read.
  float4* Y4 = reinterpret_cast<float4*>(out + (size_t)n * T);
  for (int i = tid; i < nf4; i += 256) {
    float4 o = OB4[i];
    int j = i << 2;
    float4 v = make_float4(fmaf(o.x, 0.1f, er_s[SKEW(j + 0)]),
                           fmaf(o.y, 0.1f, er_s[SKEW(j + 1)]),
                           fmaf(o.z, 0.1f, er_s[SKEW(j + 2)]),
                           fmaf(o.w, 0.1f, er_s[SKEW(j + 3)]));
    Y4[i] = v;
  }
}

// ---------------------------------------------------------------------------
// Generic fallback (any P/T): one thread per series, seasonal state in LDS.
// ---------------------------------------------------------------------------
__global__ void ets_gen(
    const float* __restrict__ alpha_, const float* __restrict__ beta_,
    const float* __restrict__ gamma_, const float* __restrict__ lvl0,
    const float* __restrict__ tr0, const float* __restrict__ seas0,
    const float* __restrict__ obs, const float* __restrict__ err,
    float* __restrict__ out, int N, int T, int P)
{
  extern __shared__ float smem[];
  int n = blockIdx.x * blockDim.x + threadIdx.x;
  if (n >= N) return;
  float* s = smem + (size_t)threadIdx.x * P;
  for (int j = 0; j < P; ++j) s[j] = seas0[(size_t)n * P + j];

  float a = alpha_[n], b = beta_[n], g = gamma_[n];
  float ia = 1.0f - a, ib = 1.0f - b, ig = 1.0f - g;
  float level = lvl0[n], trend = tr0[n];

  const float* on = obs + (size_t)n * T;
  const float* er = err + (size_t)n * T;
  float*       yo = out + (size_t)n * T;

  int idx = 0;
  for (int t = 0; t < T; ++t) {
    float onj = on[t], ej = er[t];
    float sj  = s[idx];
    float cur = level + trend + sj;
    yo[t] = fmaf(onj, 0.1f, cur);
    float lt  = level + trend;
    float nl  = fmaf(a, cur + ej, ia * lt);
    float nt  = fmaf(b, nl - level, ib * trend);
    s[idx]    = fmaf(g, ej, ig * sj);
    level = nl; trend = nt;
    if (++idx == P) idx = 0;
  }
}

extern "C" void kernel_launch(void* const* d_in, const int* in_sizes, int n_in,
                              void* d_out, int out_size, void* d_ws, size_t ws_size,
                              hipStream_t stream) {
  (void)n_in; (void)out_size; (void)d_ws; (void)ws_size;
  const float* alpha = (const float*)d_in[0];
  const float* beta  = (const float*)d_in[1];
  const float* gamma = (const float*)d_in[2];
  const float* lvl0  = (const float*)d_in[3];
  const float* tr0   = (const float*)d_in[4];
  const float* seas0 = (const float*)d_in[5];
  const float* obs   = (const float*)d_in[6];
  const float* err   = (const float*)d_in[7];
  float* y = (float*)d_out;

  int N = in_sizes[0];
  int P = in_sizes[5] / N;
  int T = in_sizes[6] / N;

  if (P == 12 && (T % 4) == 0 && T >= 12 && T <= 4096) {
    ets_wave4<<<dim3(N), dim3(256), 0, stream>>>(
        alpha, beta, gamma, lvl0, tr0, seas0, obs, err, y, T);
  } else {
    int bs = 64;
    size_t sh = (size_t)bs * (size_t)P * sizeof(float);
    ets_gen<<<dim3((N + bs - 1) / bs), dim3(bs), sh, stream>>>(
        alpha, beta, gamma, lvl0, tr0, seas0, obs, err, y, N, T, P);
  }
}